// Round 1
// baseline (420.797 us; speedup 1.0000x reference)
//
#include <hip/hip_runtime.h>
#include <math.h>

#define N_NODES  50000
#define N_EDGES  800000
#define IN_DIM   64
#define HID_DIM  64
#define N_CLS    10

// ---------------- degree / norm ----------------
__global__ void k_init_deg(float* __restrict__ deg) {
    int i = blockIdx.x * blockDim.x + threadIdx.x;
    if (i < N_NODES) deg[i] = 1.0f;  // self-loop contribution
}

__global__ void k_count_deg(const int* __restrict__ dst, float* __restrict__ deg) {
    int e = blockIdx.x * blockDim.x + threadIdx.x;
    if (e < N_EDGES) atomicAdd(&deg[dst[e]], 1.0f);
}

__global__ void k_dinv(float* __restrict__ deg) {
    int i = blockIdx.x * blockDim.x + threadIdx.x;
    if (i < N_NODES) {
        float d = deg[i];
        deg[i] = (d > 0.0f) ? rsqrtf(d) : 0.0f;
    }
}

// ---------------- xl = x @ W1  (N x 64) @ (64 x 64) ----------------
// block = 256 threads -> 4 rows, 64 cols each. W1 staged in LDS.
__global__ __launch_bounds__(256) void k_xw64(const float* __restrict__ x,
                                              const float* __restrict__ W,
                                              float* __restrict__ out) {
    __shared__ float sW[IN_DIM * HID_DIM];
    int tid = threadIdx.x;
    for (int i = tid; i < IN_DIM * HID_DIM; i += 256) sW[i] = W[i];
    __syncthreads();
    int col = tid & 63;
    int row = blockIdx.x * 4 + (tid >> 6);
    if (row >= N_NODES) return;
    const float* xr = x + (size_t)row * IN_DIM;
    float acc = 0.0f;
#pragma unroll
    for (int k = 0; k < IN_DIM; ++k) acc += xr[k] * sW[k * HID_DIM + col];
    out[(size_t)row * HID_DIM + col] = acc;
}

// ---------------- self-loop init: h[i,d] = xl[i,d] * dinv[i]^2 ----------------
__global__ void k_selfloop64(const float* __restrict__ xl, const float* __restrict__ dinv,
                             float* __restrict__ h) {
    int idx = blockIdx.x * blockDim.x + threadIdx.x;
    if (idx >= N_NODES * 64) return;
    int i = idx >> 6;
    float dv = dinv[i];
    h[idx] = xl[idx] * dv * dv;
}

// ---------------- edge aggregation, 64-dim: one wave per edge ----------------
__global__ void k_agg64(const int* __restrict__ src, const int* __restrict__ dst,
                        const float* __restrict__ dinv, const float* __restrict__ xl,
                        float* __restrict__ h) {
    long long idx = (long long)blockIdx.x * blockDim.x + threadIdx.x;
    if (idx >= (long long)N_EDGES * 64) return;
    int e = (int)(idx >> 6);
    int d = (int)(idx & 63);
    int s = src[e], t = dst[e];            // wave-uniform loads
    float norm = dinv[s] * dinv[t];
    atomicAdd(&h[(size_t)t * 64 + d], xl[(size_t)s * 64 + d] * norm);
}

// ---------------- relu(h + b1) ----------------
__global__ void k_relu_bias(float* __restrict__ h, const float* __restrict__ b) {
    int idx = blockIdx.x * blockDim.x + threadIdx.x;
    if (idx >= N_NODES * 64) return;
    h[idx] = fmaxf(h[idx] + b[idx & 63], 0.0f);
}

// ---------------- hl = h @ W2  (N x 64) @ (64 x 10) ----------------
__global__ __launch_bounds__(256) void k_xw10(const float* __restrict__ h,
                                              const float* __restrict__ W,
                                              float* __restrict__ out) {
    __shared__ float sW[HID_DIM * N_CLS];
    int tid = threadIdx.x;
    for (int i = tid; i < HID_DIM * N_CLS; i += 256) sW[i] = W[i];
    __syncthreads();
    int idx = blockIdx.x * 256 + tid;
    if (idx >= N_NODES * N_CLS) return;
    int row = idx / N_CLS;
    int col = idx - row * N_CLS;
    const float* hr = h + (size_t)row * HID_DIM;
    float acc = 0.0f;
#pragma unroll
    for (int k = 0; k < HID_DIM; ++k) acc += hr[k] * sW[k * N_CLS + col];
    out[idx] = acc;
}

// ---------------- self-loop init, 10-dim ----------------
__global__ void k_selfloop10(const float* __restrict__ hl, const float* __restrict__ dinv,
                             float* __restrict__ lg) {
    int idx = blockIdx.x * blockDim.x + threadIdx.x;
    if (idx >= N_NODES * N_CLS) return;
    int i = idx / N_CLS;
    float dv = dinv[i];
    lg[idx] = hl[idx] * dv * dv;
}

// ---------------- edge aggregation, 10-dim ----------------
__global__ void k_agg10(const int* __restrict__ src, const int* __restrict__ dst,
                        const float* __restrict__ dinv, const float* __restrict__ hl,
                        float* __restrict__ lg) {
    long long idx = (long long)blockIdx.x * blockDim.x + threadIdx.x;
    if (idx >= (long long)N_EDGES * N_CLS) return;
    int e = (int)(idx / N_CLS);
    int d = (int)(idx - (long long)e * N_CLS);
    int s = src[e], t = dst[e];
    float norm = dinv[s] * dinv[t];
    atomicAdd(&lg[(size_t)t * N_CLS + d], hl[(size_t)s * N_CLS + d] * norm);
}

// ---------------- log_softmax(lg + b2) ----------------
__global__ void k_logsoftmax(const float* __restrict__ lg, const float* __restrict__ b2,
                             float* __restrict__ out) {
    int i = blockIdx.x * blockDim.x + threadIdx.x;
    if (i >= N_NODES) return;
    float v[N_CLS];
    float m = -INFINITY;
#pragma unroll
    for (int c = 0; c < N_CLS; ++c) {
        v[c] = lg[(size_t)i * N_CLS + c] + b2[c];
        m = fmaxf(m, v[c]);
    }
    float s = 0.0f;
#pragma unroll
    for (int c = 0; c < N_CLS; ++c) s += expf(v[c] - m);
    float ls = logf(s);
#pragma unroll
    for (int c = 0; c < N_CLS; ++c) out[(size_t)i * N_CLS + c] = v[c] - m - ls;
}

extern "C" void kernel_launch(void* const* d_in, const int* in_sizes, int n_in,
                              void* d_out, int out_size, void* d_ws, size_t ws_size,
                              hipStream_t stream) {
    const float* x  = (const float*)d_in[0];
    const int*   ei = (const int*)d_in[1];
    const float* W1 = (const float*)d_in[2];
    const float* b1 = (const float*)d_in[3];
    const float* W2 = (const float*)d_in[4];
    const float* b2 = (const float*)d_in[5];
    float* out = (float*)d_out;

    const int* src = ei;             // edge_index[0]
    const int* dst = ei + N_EDGES;   // edge_index[1]

    // workspace layout (floats). hl/lg alias the xl region (xl dead by then).
    float* ws   = (float*)d_ws;
    float* dinv = ws;                      // 50000 (padded to 50048)
    float* xl   = ws + 50048;              // 3,200,000
    float* h    = xl + (size_t)N_NODES * 64; // 3,200,000
    float* hl   = xl;                      // 500,000  (aliases dead xl)
    float* lg   = xl + (size_t)N_NODES * N_CLS; // 500,000

    const int B = 256;
    int g_nodes   = (N_NODES + B - 1) / B;                 // 196
    int g_edges   = (N_EDGES + B - 1) / B;                 // 3125
    int g_n64     = (N_NODES * 64 + B - 1) / B;            // 12500
    int g_rows4   = (N_NODES + 3) / 4;                     // 12500
    int g_n10     = (N_NODES * N_CLS + B - 1) / B;         // 1954
    long long e64 = (long long)N_EDGES * 64;
    int g_e64     = (int)((e64 + B - 1) / B);              // 200000
    long long e10 = (long long)N_EDGES * N_CLS;
    int g_e10     = (int)((e10 + B - 1) / B);              // 31250

    k_init_deg  <<<g_nodes, B, 0, stream>>>(dinv);
    k_count_deg <<<g_edges, B, 0, stream>>>(dst, dinv);
    k_dinv      <<<g_nodes, B, 0, stream>>>(dinv);

    k_xw64      <<<g_rows4, B, 0, stream>>>(x, W1, xl);
    k_selfloop64<<<g_n64,   B, 0, stream>>>(xl, dinv, h);
    k_agg64     <<<g_e64,   B, 0, stream>>>(src, dst, dinv, xl, h);
    k_relu_bias <<<g_n64,   B, 0, stream>>>(h, b1);

    k_xw10      <<<g_n10,   B, 0, stream>>>(h, W2, hl);
    k_selfloop10<<<g_n10,   B, 0, stream>>>(hl, dinv, lg);
    k_agg10     <<<g_e10,   B, 0, stream>>>(src, dst, dinv, hl, lg);

    k_logsoftmax<<<g_nodes, B, 0, stream>>>(lg, b2, out);
}

// Round 2
// 414.242 us; speedup vs baseline: 1.0158x; 1.0158x over previous
//
#include <hip/hip_runtime.h>
#include <math.h>

#define N_NODES  50000
#define N_EDGES  800000
#define IN_DIM   64
#define HID_DIM  64
#define N_CLS    10
#define SCAN_T   1024

// ---------------- zero counters ----------------
__global__ void k_zero(int* __restrict__ cnt, int* __restrict__ cursor) {
    int i = blockIdx.x * blockDim.x + threadIdx.x;
    if (i < N_NODES) { cnt[i] = 0; cursor[i] = 0; }
}

// ---------------- histogram of dst ----------------
__global__ void k_hist(const int* __restrict__ dst, int* __restrict__ cnt) {
    int e = blockIdx.x * blockDim.x + threadIdx.x;
    if (e < N_EDGES) atomicAdd(&cnt[dst[e]], 1);
}

// ---------------- single-block exclusive scan + dinv ----------------
// off[i] = sum_{j<i} cnt[j]; off[N]=E. dinv[i] = rsqrt(cnt[i]+1)  (+1 = self-loop)
__global__ __launch_bounds__(SCAN_T) void k_scan(const int* __restrict__ cnt,
                                                 int* __restrict__ off,
                                                 float* __restrict__ dinv) {
    __shared__ int ssum[SCAN_T];
    int t = threadIdx.x;
    const int ITEMS = (N_NODES + SCAN_T - 1) / SCAN_T;  // 49
    int base = t * ITEMS;
    int sum = 0;
    for (int j = 0; j < ITEMS; ++j) {
        int i = base + j;
        if (i < N_NODES) sum += cnt[i];
    }
    ssum[t] = sum;
    __syncthreads();
    for (int d = 1; d < SCAN_T; d <<= 1) {
        int v = 0;
        if (t >= d) v = ssum[t - d];
        __syncthreads();
        if (t >= d) ssum[t] += v;
        __syncthreads();
    }
    int run = (t > 0) ? ssum[t - 1] : 0;
    for (int j = 0; j < ITEMS; ++j) {
        int i = base + j;
        if (i < N_NODES) {
            int c = cnt[i];
            off[i] = run;
            run += c;
            dinv[i] = rsqrtf((float)(c + 1));
        }
    }
    if (t == SCAN_T - 1) off[N_NODES] = run;  // == N_EDGES
}

// ---------------- scatter edges into CSR, precompute norm ----------------
__global__ void k_scatter(const int* __restrict__ src, const int* __restrict__ dst,
                          const int* __restrict__ off, int* __restrict__ cursor,
                          const float* __restrict__ dinv,
                          int* __restrict__ csr_src, float* __restrict__ csr_w) {
    int e = blockIdx.x * blockDim.x + threadIdx.x;
    if (e >= N_EDGES) return;
    int s = src[e], t = dst[e];
    int p = atomicAdd(&cursor[t], 1);
    int slot = off[t] + p;
    csr_src[slot] = s;
    csr_w[slot] = dinv[s] * dinv[t];
}

// ---------------- xl = x @ W1  (N x 64)(64 x 64), W1 in LDS ----------------
__global__ __launch_bounds__(256) void k_xw64(const float* __restrict__ x,
                                              const float* __restrict__ W,
                                              float* __restrict__ out) {
    __shared__ float sW[IN_DIM * HID_DIM];
    int tid = threadIdx.x;
    for (int i = tid; i < IN_DIM * HID_DIM; i += 256) sW[i] = W[i];
    __syncthreads();
    int col = tid & 63;
    int row = blockIdx.x * 4 + (tid >> 6);
    if (row >= N_NODES) return;
    const float* xr = x + (size_t)row * IN_DIM;
    float acc = 0.0f;
#pragma unroll
    for (int k = 0; k < IN_DIM; ++k) acc += xr[k] * sW[k * HID_DIM + col];
    out[(size_t)row * HID_DIM + col] = acc;
}

// ---------------- layer-1 gather: h = relu(S·xl + b1), wave per node ----------------
__global__ __launch_bounds__(256) void k_gather64(const float* __restrict__ xl,
                                                  const int* __restrict__ csr_src,
                                                  const float* __restrict__ csr_w,
                                                  const int* __restrict__ off,
                                                  const float* __restrict__ dinv,
                                                  const float* __restrict__ b1,
                                                  float* __restrict__ h) {
    int node = blockIdx.x * 4 + (threadIdx.x >> 6);
    int d = threadIdx.x & 63;
    if (node >= N_NODES) return;
    int beg = off[node], end = off[node + 1];
    float dv = dinv[node];
    float acc = xl[(size_t)node * 64 + d] * dv * dv;  // self-loop
    for (int j = beg; j < end; ++j) {
        int s = csr_src[j];          // wave-uniform -> broadcast
        float w = csr_w[j];
        acc += xl[(size_t)s * 64 + d] * w;
    }
    h[(size_t)node * 64 + d] = fmaxf(acc + b1[d], 0.0f);
}

// ---------------- hl = h @ W2  (N x 64)(64 x 10), W2 in LDS ----------------
__global__ __launch_bounds__(256) void k_xw10(const float* __restrict__ h,
                                              const float* __restrict__ W,
                                              float* __restrict__ out) {
    __shared__ float sW[HID_DIM * N_CLS];
    int tid = threadIdx.x;
    for (int i = tid; i < HID_DIM * N_CLS; i += 256) sW[i] = W[i];
    __syncthreads();
    int idx = blockIdx.x * 256 + tid;
    if (idx >= N_NODES * N_CLS) return;
    int row = idx / N_CLS;
    int col = idx - row * N_CLS;
    const float* hr = h + (size_t)row * HID_DIM;
    float acc = 0.0f;
#pragma unroll
    for (int k = 0; k < HID_DIM; ++k) acc += hr[k] * sW[k * N_CLS + col];
    out[idx] = acc;
}

// ---------------- layer-2 gather + b2 + log_softmax, 16-lane group per node ----------------
__global__ __launch_bounds__(256) void k_gather10(const float* __restrict__ hl,
                                                  const int* __restrict__ csr_src,
                                                  const float* __restrict__ csr_w,
                                                  const int* __restrict__ off,
                                                  const float* __restrict__ dinv,
                                                  const float* __restrict__ b2,
                                                  float* __restrict__ out) {
    int t = threadIdx.x;
    int node = blockIdx.x * 16 + (t >> 4);
    int d = t & 15;
    if (node >= N_NODES) return;
    bool act = d < N_CLS;
    int beg = off[node], end = off[node + 1];
    float dv = dinv[node];
    float acc = act ? hl[(size_t)node * N_CLS + d] * dv * dv : 0.0f;
    for (int j = beg; j < end; ++j) {
        int s = csr_src[j];
        float w = csr_w[j];
        if (act) acc += hl[(size_t)s * N_CLS + d] * w;
    }
    float v = act ? acc + b2[d] : -INFINITY;
    // 16-lane (xor<=8 stays in aligned group) max + sum reductions
    float m = v;
#pragma unroll
    for (int k = 1; k < 16; k <<= 1) m = fmaxf(m, __shfl_xor(m, k, 64));
    float ex = act ? expf(v - m) : 0.0f;
    float ssum = ex;
#pragma unroll
    for (int k = 1; k < 16; k <<= 1) ssum += __shfl_xor(ssum, k, 64);
    if (act) out[(size_t)node * N_CLS + d] = v - m - logf(ssum);
}

extern "C" void kernel_launch(void* const* d_in, const int* in_sizes, int n_in,
                              void* d_out, int out_size, void* d_ws, size_t ws_size,
                              hipStream_t stream) {
    const float* x  = (const float*)d_in[0];
    const int*   ei = (const int*)d_in[1];
    const float* W1 = (const float*)d_in[2];
    const float* b1 = (const float*)d_in[3];
    const float* W2 = (const float*)d_in[4];
    const float* b2 = (const float*)d_in[5];
    float* out = (float*)d_out;

    const int* src = ei;             // edge_index[0]
    const int* dst = ei + N_EDGES;   // edge_index[1]

    // workspace layout (~32.8 MB)
    int*   cnt     = (int*)d_ws;                  // 50048
    int*   cursor  = cnt + 50048;                 // 50048
    int*   off     = cursor + 50048;              // 50056 (N+1 used)
    int*   csr_src = off + 50056;                 // 800000
    float* csr_w   = (float*)(csr_src + N_EDGES); // 800000
    float* dinv    = csr_w + N_EDGES;             // 50048
    float* xl      = dinv + 50048;                // 3,200,000
    float* h       = xl + (size_t)N_NODES * 64;   // 3,200,000
    float* hl      = xl;                          // aliases dead xl

    const int B = 256;
    int g_nodes = (N_NODES + B - 1) / B;          // 196
    int g_edges = (N_EDGES + B - 1) / B;          // 3125
    int g_rows4 = (N_NODES + 3) / 4;              // 12500
    int g_n10   = (N_NODES * N_CLS + B - 1) / B;  // 1954
    int g_g10   = (N_NODES + 15) / 16;            // 3125

    k_zero    <<<g_nodes, B, 0, stream>>>(cnt, cursor);
    k_hist    <<<g_edges, B, 0, stream>>>(dst, cnt);
    k_scan    <<<1, SCAN_T, 0, stream>>>(cnt, off, dinv);
    k_xw64    <<<g_rows4, B, 0, stream>>>(x, W1, xl);
    k_scatter <<<g_edges, B, 0, stream>>>(src, dst, off, cursor, dinv, csr_src, csr_w);
    k_gather64<<<g_rows4, B, 0, stream>>>(xl, csr_src, csr_w, off, dinv, b1, h);
    k_xw10    <<<g_n10,   B, 0, stream>>>(h, W2, hl);
    k_gather10<<<g_g10,   B, 0, stream>>>(hl, csr_src, csr_w, off, dinv, b2, out);
}

// Round 3
// 261.856 us; speedup vs baseline: 1.6070x; 1.5819x over previous
//
#include <hip/hip_runtime.h>
#include <math.h>

#define N_NODES  50000
#define N_EDGES  800000
#define IN_DIM   64
#define HID_DIM  64
#define N_CLS    10
#define NBLK     ((N_NODES + 255) / 256)   // 196 scan blocks

// ---------------- zero counters ----------------
__global__ void k_zero(int* __restrict__ cnt, int* __restrict__ cursor) {
    int i = blockIdx.x * blockDim.x + threadIdx.x;
    if (i < N_NODES) { cnt[i] = 0; cursor[i] = 0; }
}

// ---------------- histogram of dst ----------------
__global__ void k_hist(const int* __restrict__ dst, int* __restrict__ cnt) {
    int e = blockIdx.x * blockDim.x + threadIdx.x;
    if (e < N_EDGES) atomicAdd(&cnt[dst[e]], 1);
}

// ---------------- scan phase A: per-block sums ----------------
__global__ __launch_bounds__(256) void k_blocksum(const int* __restrict__ cnt,
                                                  int* __restrict__ partial) {
    __shared__ int sw[4];
    int t = threadIdx.x;
    int i = blockIdx.x * 256 + t;
    int c = (i < N_NODES) ? cnt[i] : 0;
#pragma unroll
    for (int k = 1; k < 64; k <<= 1) c += __shfl_xor(c, k, 64);
    if ((t & 63) == 0) sw[t >> 6] = c;
    __syncthreads();
    if (t == 0) partial[blockIdx.x] = sw[0] + sw[1] + sw[2] + sw[3];
}

// ---------------- scan phase B: scan the partials (tiny) ----------------
__global__ __launch_bounds__(256) void k_scanpart(int* __restrict__ partial,
                                                  int* __restrict__ off) {
    __shared__ int s[256];
    int t = threadIdx.x;
    int v = (t < NBLK) ? partial[t] : 0;
    s[t] = v;
    __syncthreads();
    for (int d = 1; d < 256; d <<= 1) {
        int u = 0;
        if (t >= d) u = s[t - d];
        __syncthreads();
        if (t >= d) s[t] += u;
        __syncthreads();
    }
    if (t < NBLK) partial[t] = s[t] - v;   // exclusive
    if (t == 0) off[N_NODES] = N_EDGES;
}

// ---------------- scan phase C: in-block scan + add partial offset + dinv ----------------
__global__ __launch_bounds__(256) void k_blockscan(const int* __restrict__ cnt,
                                                   const int* __restrict__ partial,
                                                   int* __restrict__ off,
                                                   float* __restrict__ dinv) {
    __shared__ int s[256];
    int t = threadIdx.x;
    int i = blockIdx.x * 256 + t;
    int c = (i < N_NODES) ? cnt[i] : 0;
    s[t] = c;
    __syncthreads();
    for (int d = 1; d < 256; d <<= 1) {
        int u = 0;
        if (t >= d) u = s[t - d];
        __syncthreads();
        if (t >= d) s[t] += u;
        __syncthreads();
    }
    if (i < N_NODES) {
        off[i] = partial[blockIdx.x] + s[t] - c;       // exclusive
        dinv[i] = rsqrtf((float)(c + 1));              // +1 self-loop
    }
}

// ---------------- scatter edges into CSR, precompute norm ----------------
__global__ void k_scatter(const int* __restrict__ src, const int* __restrict__ dst,
                          const int* __restrict__ off, int* __restrict__ cursor,
                          const float* __restrict__ dinv,
                          int* __restrict__ csr_src, float* __restrict__ csr_w) {
    int e = blockIdx.x * blockDim.x + threadIdx.x;
    if (e >= N_EDGES) return;
    int s = src[e], t = dst[e];
    int p = atomicAdd(&cursor[t], 1);
    int slot = off[t] + p;
    csr_src[slot] = s;
    csr_w[slot] = dinv[s] * dinv[t];
}

// ---------------- xl = x @ W1  (N x 64)(64 x 64), W1 in LDS ----------------
__global__ __launch_bounds__(256) void k_xw64(const float* __restrict__ x,
                                              const float* __restrict__ W,
                                              float* __restrict__ out) {
    __shared__ float sW[IN_DIM * HID_DIM];
    int tid = threadIdx.x;
    for (int i = tid; i < IN_DIM * HID_DIM; i += 256) sW[i] = W[i];
    __syncthreads();
    int col = tid & 63;
    int row = blockIdx.x * 4 + (tid >> 6);
    if (row >= N_NODES) return;
    const float* xr = x + (size_t)row * IN_DIM;
    float acc = 0.0f;
#pragma unroll
    for (int k = 0; k < IN_DIM; ++k) acc += xr[k] * sW[k * HID_DIM + col];
    out[(size_t)row * HID_DIM + col] = acc;
}

// ---------------- layer-1 gather: h = relu(S·xl + b1), wave per node ----------------
__global__ __launch_bounds__(256) void k_gather64(const float* __restrict__ xl,
                                                  const int* __restrict__ csr_src,
                                                  const float* __restrict__ csr_w,
                                                  const int* __restrict__ off,
                                                  const float* __restrict__ dinv,
                                                  const float* __restrict__ b1,
                                                  float* __restrict__ h) {
    int node = blockIdx.x * 4 + (threadIdx.x >> 6);
    int d = threadIdx.x & 63;
    if (node >= N_NODES) return;
    int beg = off[node], end = off[node + 1];
    float dv = dinv[node];
    float acc = xl[(size_t)node * 64 + d] * dv * dv;  // self-loop
    int j = beg;
    // unroll x4: independent gathers in flight (latency-bound loop)
    for (; j + 4 <= end; j += 4) {
        int s0 = csr_src[j],     s1 = csr_src[j + 1];
        int s2 = csr_src[j + 2], s3 = csr_src[j + 3];
        float w0 = csr_w[j],     w1 = csr_w[j + 1];
        float w2 = csr_w[j + 2], w3 = csr_w[j + 3];
        float v0 = xl[(size_t)s0 * 64 + d];
        float v1 = xl[(size_t)s1 * 64 + d];
        float v2 = xl[(size_t)s2 * 64 + d];
        float v3 = xl[(size_t)s3 * 64 + d];
        acc += v0 * w0 + v1 * w1 + v2 * w2 + v3 * w3;
    }
    for (; j < end; ++j)
        acc += xl[(size_t)csr_src[j] * 64 + d] * csr_w[j];
    h[(size_t)node * 64 + d] = fmaxf(acc + b1[d], 0.0f);
}

// ---------------- hl = h @ W2  (N x 64)(64 x 10), W2 in LDS ----------------
__global__ __launch_bounds__(256) void k_xw10(const float* __restrict__ h,
                                              const float* __restrict__ W,
                                              float* __restrict__ out) {
    __shared__ float sW[HID_DIM * N_CLS];
    int tid = threadIdx.x;
    for (int i = tid; i < HID_DIM * N_CLS; i += 256) sW[i] = W[i];
    __syncthreads();
    int idx = blockIdx.x * 256 + tid;
    if (idx >= N_NODES * N_CLS) return;
    int row = idx / N_CLS;
    int col = idx - row * N_CLS;
    const float* hr = h + (size_t)row * HID_DIM;
    float acc = 0.0f;
#pragma unroll
    for (int k = 0; k < HID_DIM; ++k) acc += hr[k] * sW[k * N_CLS + col];
    out[idx] = acc;
}

// ---------------- layer-2 gather + b2 + log_softmax, 16-lane group per node ----------------
__global__ __launch_bounds__(256) void k_gather10(const float* __restrict__ hl,
                                                  const int* __restrict__ csr_src,
                                                  const float* __restrict__ csr_w,
                                                  const int* __restrict__ off,
                                                  const float* __restrict__ dinv,
                                                  const float* __restrict__ b2,
                                                  float* __restrict__ out) {
    int t = threadIdx.x;
    int node = blockIdx.x * 16 + (t >> 4);
    int d = t & 15;
    if (node >= N_NODES) return;
    bool act = d < N_CLS;
    int beg = off[node], end = off[node + 1];
    float dv = dinv[node];
    float acc = act ? hl[(size_t)node * N_CLS + d] * dv * dv : 0.0f;
    for (int j = beg; j < end; ++j) {
        int s = csr_src[j];
        float w = csr_w[j];
        if (act) acc += hl[(size_t)s * N_CLS + d] * w;
    }
    float v = act ? acc + b2[d] : -INFINITY;
    float m = v;
#pragma unroll
    for (int k = 1; k < 16; k <<= 1) m = fmaxf(m, __shfl_xor(m, k, 64));
    float ex = act ? expf(v - m) : 0.0f;
    float ssum = ex;
#pragma unroll
    for (int k = 1; k < 16; k <<= 1) ssum += __shfl_xor(ssum, k, 64);
    if (act) out[(size_t)node * N_CLS + d] = v - m - logf(ssum);
}

extern "C" void kernel_launch(void* const* d_in, const int* in_sizes, int n_in,
                              void* d_out, int out_size, void* d_ws, size_t ws_size,
                              hipStream_t stream) {
    const float* x  = (const float*)d_in[0];
    const int*   ei = (const int*)d_in[1];
    const float* W1 = (const float*)d_in[2];
    const float* b1 = (const float*)d_in[3];
    const float* W2 = (const float*)d_in[4];
    const float* b2 = (const float*)d_in[5];
    float* out = (float*)d_out;

    const int* src = ei;             // edge_index[0]
    const int* dst = ei + N_EDGES;   // edge_index[1]

    // workspace layout
    int*   cnt     = (int*)d_ws;                  // 50048
    int*   cursor  = cnt + 50048;                 // 50048
    int*   off     = cursor + 50048;              // 50056 (N+1 used)
    int*   partial = off + 50056;                 // 256
    int*   csr_src = partial + 256;               // 800000
    float* csr_w   = (float*)(csr_src + N_EDGES); // 800000
    float* dinv    = csr_w + N_EDGES;             // 50048
    float* xl      = dinv + 50048;                // 3,200,000
    float* h       = xl + (size_t)N_NODES * 64;   // 3,200,000
    float* hl      = xl;                          // aliases dead xl

    const int B = 256;
    int g_nodes = (N_NODES + B - 1) / B;          // 196
    int g_edges = (N_EDGES + B - 1) / B;          // 3125
    int g_rows4 = (N_NODES + 3) / 4;              // 12500
    int g_n10   = (N_NODES * N_CLS + B - 1) / B;  // 1954
    int g_g10   = (N_NODES + 15) / 16;            // 3125

    k_zero     <<<g_nodes, B, 0, stream>>>(cnt, cursor);
    k_hist     <<<g_edges, B, 0, stream>>>(dst, cnt);
    k_blocksum <<<NBLK,    B, 0, stream>>>(cnt, partial);
    k_scanpart <<<1,       B, 0, stream>>>(partial, off);
    k_blockscan<<<NBLK,    B, 0, stream>>>(cnt, partial, off, dinv);
    k_xw64     <<<g_rows4, B, 0, stream>>>(x, W1, xl);
    k_scatter  <<<g_edges, B, 0, stream>>>(src, dst, off, cursor, dinv, csr_src, csr_w);
    k_gather64 <<<g_rows4, B, 0, stream>>>(xl, csr_src, csr_w, off, dinv, b1, h);
    k_xw10     <<<g_n10,   B, 0, stream>>>(h, W2, hl);
    k_gather10 <<<g_g10,   B, 0, stream>>>(hl, csr_src, csr_w, off, dinv, b2, out);
}